// Round 14
// baseline (128.631 us; speedup 1.0000x reference)
//
#include <hip/hip_runtime.h>
#include <stdint.h>
#include <stddef.h>

#define B_TOT   16384
#define NUM_IN  256
#define N_NODES 1024
#define NN      768
#define K       8
#define NUM_OUT 64
#define NB      64      // batch elements per block (= lanes)
#define MAXL    800     // max levels we can represent (true max = 768)
#define TPB     1024    // eval threads per block (16 waves, 4/SIMD)
#define WPB     16      // waves per eval block

typedef _Float16 h2 __attribute__((ext_vector_type(2)));

// 64-byte schedule record, one per non-input node, sorted by dependency level.
// p[k] = swizzled LDS BYTE base for pred k: (id*64 + ((id&31)<<1))*2; lane's
// byte address is p[k] ^ (lane<<1). Weights are fp16 pairs (response folded).
struct Rec {
  uint32_t p[8];                 // byte-swizzled pred bases
  uint32_t w01, w23, w45, w67;   // fp16x2 packed weights
  uint32_t outPh;                // byte-swizzled output base
  float    bias;
  uint32_t pad0, pad1;
};
static_assert(sizeof(Rec) == 64, "Rec must be 64B");

// ---------------------------------------------------------------------------
// Setup: exact dependency levels via Jacobi ping-pong Bellman-Ford (1 barrier
// per iter; convergence checked every 4th iter with the R3-proven 3-barrier
// flag protocol). HW-validated across graph replays in R13. Then counting-
// sort by level, emit packed records.
// ---------------------------------------------------------------------------
__global__ __launch_bounds__(NN)
void setup_kernel(const int* __restrict__ in_idx,
                  const float* __restrict__ edge_w,
                  const float* __restrict__ bias,
                  const float* __restrict__ response,
                  const int* __restrict__ out_idx,
                  int* __restrict__ g_nlev,
                  int* __restrict__ g_loff,
                  Rec* __restrict__ recs)
{
  __shared__ int lvlA[N_NODES];
  __shared__ int lvlB[N_NODES];
  __shared__ int hist[MAXL];
  __shared__ int cnt[MAXL];
  __shared__ int offs[MAXL + 2];
  __shared__ int changed;
  __shared__ int maxlv;

  const int t = threadIdx.x;

  for (int i = t; i < N_NODES; i += NN) { lvlA[i] = 0; lvlB[i] = 0; }
  for (int i = t; i < MAXL; i += NN) { hist[i] = 0; cnt[i] = 0; }
  if (t == 0) maxlv = 0;

  int idxs[K];
#pragma unroll
  for (int k = 0; k < K; ++k)
    idxs[k] = in_idx[t * K + k];       // deg == K for all nodes (node id >= 256)
  __syncthreads();

  int* cur = lvlA;
  int* nxt = lvlB;
  int L = 1;
  for (int it = 0; it < 800; ++it) {
    int nl = 0;
#pragma unroll
    for (int k = 0; k < K; ++k) {
      int l = cur[idxs[k]];
      nl = (l > nl) ? l : nl;
    }
    nl += 1;
    nxt[NUM_IN + t] = nl;
    L = nl;
    if ((it & 3) == 3) {
      __syncthreads();               // (1) nxt writes + cur reads done
      if (t == 0) changed = 0;
      __syncthreads();               // (2) changed=0 visible
      if (nl != cur[NUM_IN + t]) changed = 1;
      __syncthreads();               // (3) flag final
      if (changed == 0) break;       // uniform exit; L = converged level
    } else {
      __syncthreads();               // nxt visible before it becomes cur
    }
    int* tmp = cur; cur = nxt; nxt = tmp;
  }

  atomicAdd(&hist[L], 1);
  atomicMax(&maxlv, L);
  __syncthreads();
  const int ml = maxlv;
  if (t == 0) {
    offs[1] = 0;
    for (int l = 1; l <= ml; ++l) offs[l + 1] = offs[l] + hist[l];
  }
  __syncthreads();
  const int pos = offs[L] + atomicAdd(&cnt[L], 1);

  // Build the packed record (byte-swizzled bases).
  Rec r;
#pragma unroll
  for (int k = 0; k < K; ++k) {
    uint32_t id = (uint32_t)idxs[k];
    r.p[k] = (id * 64u + ((id & 31u) << 1)) << 1;
  }
  const float rsp = response[t];
  uint16_t hw[K];
#pragma unroll
  for (int k = 0; k < K; ++k) {
    _Float16 h = (_Float16)(edge_w[t * K + k] * rsp);
    hw[k] = __builtin_bit_cast(uint16_t, h);
  }
  r.w01 = (uint32_t)hw[0] | ((uint32_t)hw[1] << 16);
  r.w23 = (uint32_t)hw[2] | ((uint32_t)hw[3] << 16);
  r.w45 = (uint32_t)hw[4] | ((uint32_t)hw[5] << 16);
  r.w67 = (uint32_t)hw[6] | ((uint32_t)hw[7] << 16);
  uint32_t oid = (uint32_t)out_idx[t];
  r.outPh = (oid * 64u + ((oid & 31u) << 1)) << 1;
  r.bias = bias[t];
  r.pad0 = 0; r.pad1 = 0;
  recs[pos] = r;

  if (t <= ml) g_loff[t] = offs[t + 1];   // g_loff[i] = start of level i+1; g_loff[ml] = NN
  if (t == 0)  g_nlev[0] = ml;
}

// ---------------------------------------------------------------------------
// Eval: one block per 64 batch elements (lane = batch element). Node values in
// 128 KiB LDS (fp16), XOR-swizzled (0 bank conflicts, HW-verified). 16 waves
// (4/SIMD). Records are loaded via per-lane VMEM broadcast (vmcnt) — NOT
// scalar SMEM — so ds_read waits stay precise (SMEM+DS share lgkmcnt with
// out-of-order completion, which forced lgkmcnt(0) drains in R9-R13).
// The next level's records are prefetched BEFORE the barrier: VMEM loads stay
// in flight across s_barrier, removing the ~200-cyc record load from each
// level's critical chain (the serial axis is the ~30 levels, not the 1-2
// nodes/wave within a level).
// ---------------------------------------------------------------------------
__global__ __launch_bounds__(TPB, 4)
void eval_kernel(const float* __restrict__ inputs,
                 const int* __restrict__ output_idx,
                 const int* __restrict__ g_nlev,
                 const int* __restrict__ g_loff,
                 const Rec* __restrict__ recs,
                 float* __restrict__ out)
{
  __shared__ _Float16 vals[N_NODES * NB];   // 128 KiB
  __shared__ int      loffs[MAXL + 1];

  const uint32_t tid  = threadIdx.x;
  const uint32_t lane = tid & 63u;
  const uint32_t wave = tid >> 6;           // 0..15
  const int      base = blockIdx.x * NB;

  const char*  vbytes  = (const char*)vals;
  char*        vbytesw = (char*)vals;
  const uint32_t lane2 = lane << 1;

  const int nlev = g_nlev[0];
  for (int i = (int)tid; i <= nlev; i += TPB) loffs[i] = g_loff[i];

  // Level-0 record prefetch (before the staging barrier; bounds from GLOBAL
  // g_loff, since the LDS loffs copy is not yet barrier-published).
  const int e0g = g_loff[1];                // level-0 range is [0, e0g)
  Rec r0, r1;
  bool h0, h1;
  {
    const int j0 = (int)wave;
    const int j1 = j0 + WPB;
    h0 = j0 < e0g;
    h1 = j1 < e0g;
    if (h0) r0 = recs[j0];                  // VMEM broadcast loads
    if (h1) r1 = recs[j1];
  }

  // Stage 64 rows x 256 input cols: thread -> (col = tid&255, c-group = tid>>8).
  const uint32_t col = tid & 255u;
  const uint32_t cg  = tid >> 8;            // 0..3
  const uint32_t swz = col * 64u + ((col & 31u) << 1);   // element index
  for (uint32_t c = cg; c < NB; c += 4) {
    float v = inputs[(size_t)(base + c) * NUM_IN + col];
    vals[swz ^ c] = (_Float16)v;
  }
  __syncthreads();

#define LOADV(r, x0,x1,x2,x3,x4,x5,x6,x7) do {                      \
    x0 = *(const _Float16*)(vbytes + ((r).p[0] ^ lane2));           \
    x1 = *(const _Float16*)(vbytes + ((r).p[1] ^ lane2));           \
    x2 = *(const _Float16*)(vbytes + ((r).p[2] ^ lane2));           \
    x3 = *(const _Float16*)(vbytes + ((r).p[3] ^ lane2));           \
    x4 = *(const _Float16*)(vbytes + ((r).p[4] ^ lane2));           \
    x5 = *(const _Float16*)(vbytes + ((r).p[5] ^ lane2));           \
    x6 = *(const _Float16*)(vbytes + ((r).p[6] ^ lane2));           \
    x7 = *(const _Float16*)(vbytes + ((r).p[7] ^ lane2));           \
  } while (0)

#if __has_builtin(__builtin_amdgcn_fdot2)
#define DOT8(r, x0,x1,x2,x3,x4,x5,x6,x7, xx) do {                                   \
    h2 v01 = {x0, x1}, v23 = {x2, x3}, v45 = {x4, x5}, v67 = {x6, x7};              \
    xx = (r).bias;                                                                  \
    xx = __builtin_amdgcn_fdot2(v01, __builtin_bit_cast(h2, (r).w01), xx, false);   \
    xx = __builtin_amdgcn_fdot2(v23, __builtin_bit_cast(h2, (r).w23), xx, false);   \
    xx = __builtin_amdgcn_fdot2(v45, __builtin_bit_cast(h2, (r).w45), xx, false);   \
    xx = __builtin_amdgcn_fdot2(v67, __builtin_bit_cast(h2, (r).w67), xx, false);   \
  } while (0)
#else
#define DOT8(r, x0,x1,x2,x3,x4,x5,x6,x7, xx) do {                                   \
    h2 w01 = __builtin_bit_cast(h2, (r).w01), w23 = __builtin_bit_cast(h2, (r).w23);\
    h2 w45 = __builtin_bit_cast(h2, (r).w45), w67 = __builtin_bit_cast(h2, (r).w67);\
    float s0 = __builtin_fmaf((float)w01.x, (float)x0, (r).bias);                   \
    float s1 = (float)w01.y * (float)x1;                                            \
    float s2 = (float)w23.x * (float)x2;                                            \
    float s3 = (float)w23.y * (float)x3;                                            \
    s0 = __builtin_fmaf((float)w45.x, (float)x4, s0);                               \
    s1 = __builtin_fmaf((float)w45.y, (float)x5, s1);                               \
    s2 = __builtin_fmaf((float)w67.x, (float)x6, s2);                               \
    s3 = __builtin_fmaf((float)w67.y, (float)x7, s3);                               \
    xx = (s0 + s1) + (s2 + s3);                                                     \
  } while (0)
#endif

#define COMPUTE(r, x0,x1,x2,x3,x4,x5,x6,x7) do {                    \
    float xx;                                                       \
    DOT8(r, x0,x1,x2,x3,x4,x5,x6,x7, xx);                           \
    const float e  = __expf(xx + xx);                               \
    const float rc = __builtin_amdgcn_rcpf(e + 1.0f);               \
    const float y  = __builtin_fmaf(-2.0f, rc, 1.0f);               \
    *(_Float16*)(vbytesw + ((r).outPh ^ lane2)) = (_Float16)y;      \
  } while (0)

  for (int l = 0; l < nlev; ++l) {
    const int beg = loffs[l], end = loffs[l + 1];

    // Main two nodes of this level (records already in registers, loaded a
    // full level ago). Issue both ds_read sets before either compute (ILP).
    _Float16 a0, a1, a2, a3, a4, a5, a6, a7;
    _Float16 b0, b1, b2, b3, b4, b5, b6, b7;
    if (h0) LOADV(r0, a0, a1, a2, a3, a4, a5, a6, a7);
    if (h1) LOADV(r1, b0, b1, b2, b3, b4, b5, b6, b7);
    if (h0) COMPUTE(r0, a0, a1, a2, a3, a4, a5, a6, a7);
    if (h1) COMPUTE(r1, b0, b1, b2, b3, b4, b5, b6, b7);

    // Rare tail: levels with more than 2*WPB nodes.
    for (int j = beg + (int)wave + 2 * WPB; j < end; j += WPB) {
      Rec rr = recs[j];
      _Float16 c0, c1, c2, c3, c4, c5, c6, c7;
      LOADV(rr, c0, c1, c2, c3, c4, c5, c6, c7);
      COMPUTE(rr, c0, c1, c2, c3, c4, c5, c6, c7);
    }

    // Prefetch next level's records BEFORE the barrier (VMEM survives it).
    if (l + 1 < nlev) {
      const int nb = loffs[l + 1], ne = loffs[l + 2];
      const int j0 = nb + (int)wave;
      const int j1 = j0 + WPB;
      h0 = j0 < ne;
      h1 = j1 < ne;
      if (h0) r0 = recs[j0];
      if (h1) r1 = recs[j1];
    }
    __syncthreads();
  }

  // Emit outputs: out[(base+b)*64 + lane] (coalesced 256B/wave stores).
  const uint32_t oid  = (uint32_t)output_idx[lane];
  const uint32_t oswz = oid * 64u + ((oid & 31u) << 1);   // element index
  for (uint32_t k = 0; k < 4; ++k) {
    const uint32_t b = wave + k * 16u;
    float v = (float)vals[oswz ^ b];
    out[(size_t)(base + b) * NUM_OUT + lane] = v;
  }
}

// ---------------------------------------------------------------------------
extern "C" void kernel_launch(void* const* d_in, const int* in_sizes, int n_in,
                              void* d_out, int out_size, void* d_ws, size_t ws_size,
                              hipStream_t stream)
{
  (void)in_sizes; (void)n_in; (void)out_size; (void)ws_size;

  const float* inputs     = (const float*)d_in[0];
  const float* edge_w     = (const float*)d_in[1];
  const float* bias       = (const float*)d_in[2];
  const float* response   = (const float*)d_in[3];
  const int*   in_idx     = (const int*)d_in[4];
  // d_in[5] = edge_mask: all-true for this graph (deg = min(K, node) = K since
  // every non-input node id >= 256 > K), so it is ignored.
  const int*   out_idx    = (const int*)d_in[6];
  const int*   output_idx = (const int*)d_in[7];
  float*       out        = (float*)d_out;

  char* ws = (char*)d_ws;
  int* g_nlev = (int*)ws;                 // 1 int
  int* g_loff = (int*)(ws + 256);         // up to 800 ints
  Rec* recs   = (Rec*)(ws + 8192);        // 768 * 64B = 48 KiB

  hipLaunchKernelGGL(setup_kernel, dim3(1), dim3(NN), 0, stream,
                     in_idx, edge_w, bias, response, out_idx,
                     g_nlev, g_loff, recs);
  hipLaunchKernelGGL(eval_kernel, dim3(B_TOT / NB), dim3(TPB), 0, stream,
                     inputs, output_idx, g_nlev, g_loff, recs, out);
}